// Round 4
// baseline (801.560 us; speedup 1.0000x reference)
//
#include <hip/hip_runtime.h>
#include <hip/hip_bf16.h>
#include <cstdint>

// Block: B=4, S=2048, E=1024, H=16, DH=64, DF=4096.  M = B*S = 8192 rows.
// All GEMMs: C = A[M,K] * Bt[N,K]^T via mfma_f32_16x16x32_bf16, fp32 acc.

typedef __bf16 bf16_t;
typedef __attribute__((ext_vector_type(8))) __bf16 bf16x8;
typedef __attribute__((ext_vector_type(4))) __bf16 bf16x4;
typedef __attribute__((ext_vector_type(4))) float f32x4;

#define LOG2E 1.4426950408889634f

static __device__ __forceinline__ void gll16(const void* g, void* l) {
  __builtin_amdgcn_global_load_lds(
      (const __attribute__((address_space(1))) void*)g,
      (__attribute__((address_space(3))) void*)l, 16, 0, 0);
}

// ---------------- transpose + fp32->bf16 convert ----------------
__global__ __launch_bounds__(256)
void transpose_cvt(const float* __restrict__ in, bf16_t* __restrict__ out,
                   int R, int C, long in_batch, long out_batch)
{
  __shared__ float tile[64][65];
  const float* inp = in + (long)blockIdx.z * in_batch;
  bf16_t* outp = out + (long)blockIdx.z * out_batch;
  const int c0 = blockIdx.x * 64, r0 = blockIdx.y * 64;
  for (int rr = threadIdx.y; rr < 64; rr += 4)
    tile[rr][threadIdx.x] = inp[(long)(r0 + rr) * C + c0 + threadIdx.x];
  __syncthreads();
  for (int cc = threadIdx.y; cc < 64; cc += 4)
    outp[(long)(c0 + cc) * R + r0 + threadIdx.x] = (bf16_t)tile[threadIdx.x][cc];
}

// ---------------- LayerNorm (fp32 in, bf16 out) ----------------
__global__ __launch_bounds__(256)
void ln_kernel(const float* __restrict__ x, const float* __restrict__ g,
               const float* __restrict__ be, bf16_t* __restrict__ out)
{
  const long row = blockIdx.x;
  const float4 v = ((const float4*)(x + row * 1024))[threadIdx.x];
  float s  = v.x + v.y + v.z + v.w;
  float s2 = v.x*v.x + v.y*v.y + v.z*v.z + v.w*v.w;
  #pragma unroll
  for (int m = 1; m < 64; m <<= 1) {
    s  += __shfl_xor(s, m, 64);
    s2 += __shfl_xor(s2, m, 64);
  }
  __shared__ float red[8];
  const int w = threadIdx.x >> 6, lane = threadIdx.x & 63;
  if (lane == 0) { red[w] = s; red[4 + w] = s2; }
  __syncthreads();
  s  = red[0] + red[1] + red[2] + red[3];
  s2 = red[4] + red[5] + red[6] + red[7];
  const float mu = s * (1.f / 1024.f);
  const float rs = rsqrtf(s2 * (1.f / 1024.f) - mu * mu + 1e-5f);
  const int c = threadIdx.x * 4;
  bf16x4 o;
  o[0] = (bf16_t)((v.x - mu) * rs * g[c+0] + be[c+0]);
  o[1] = (bf16_t)((v.y - mu) * rs * g[c+1] + be[c+1]);
  o[2] = (bf16_t)((v.z - mu) * rs * g[c+2] + be[c+2]);
  o[3] = (bf16_t)((v.w - mu) * rs * g[c+3] + be[c+3]);
  *(bf16x4*)(out + row * 1024 + c) = o;
}

// ---------------- generic bf16 GEMM, 128x128 tile, BK=32, 4 waves ----------
template<int EPI>
__global__ __launch_bounds__(256)
void gemm16(const bf16_t* __restrict__ A, const bf16_t* __restrict__ Bt,
            const float* __restrict__ bias, const float* __restrict__ res,
            float* __restrict__ outF,
            bf16_t* __restrict__ outQ, bf16_t* __restrict__ outK, bf16_t* __restrict__ outV,
            int M, int N, int K)
{
  __shared__ __align__(16) bf16_t As[128 * 32];
  __shared__ __align__(16) bf16_t Bs[128 * 32];
  const int tid = threadIdx.x, lane = tid & 63, w = tid >> 6;
  const int wr = w >> 1, wc = w & 1;
  const long row0 = (long)blockIdx.y * 128;
  const long col0 = (long)blockIdx.x * 128;
  const int rsub = lane >> 2;
  const int csub = (lane & 3) * 8;
  f32x4 acc[4][4] = {};
  for (long k0 = 0; k0 < K; k0 += 32) {
    #pragma unroll
    for (int i = 0; i < 2; ++i) {
      const int c = i * 4 + w;
      gll16(A  + (row0 + c * 16 + rsub) * (long)K + k0 + csub, (char*)As + c * 1024);
      gll16(Bt + (col0 + c * 16 + rsub) * (long)K + k0 + csub, (char*)Bs + c * 1024);
    }
    __syncthreads();
    const int kof = (lane >> 4) * 8;
    bf16x8 af[4], bfr[4];
    #pragma unroll
    for (int m = 0; m < 4; ++m)
      af[m] = *(const bf16x8*)(As + (wr * 64 + m * 16 + (lane & 15)) * 32 + kof);
    #pragma unroll
    for (int n = 0; n < 4; ++n)
      bfr[n] = *(const bf16x8*)(Bs + (wc * 64 + n * 16 + (lane & 15)) * 32 + kof);
    #pragma unroll
    for (int m = 0; m < 4; ++m)
      #pragma unroll
      for (int n = 0; n < 4; ++n)
        acc[m][n] = __builtin_amdgcn_mfma_f32_16x16x32_bf16(af[m], bfr[n], acc[m][n], 0, 0, 0);
    __syncthreads();
  }
  #pragma unroll
  for (int m = 0; m < 4; ++m) {
    #pragma unroll
    for (int n = 0; n < 4; ++n) {
      const long cc = col0 + wc * 64 + n * 16 + (lane & 15);
      #pragma unroll
      for (int r = 0; r < 4; ++r) {
        const long rr = row0 + wr * 64 + m * 16 + (lane >> 4) * 4 + r;
        const float v = acc[m][n][r];
        if constexpr (EPI == 0) {
          const int which = (int)(cc >> 10);
          const int hh = (int)((cc >> 6) & 15);
          const int d  = (int)(cc & 63);
          const long b = rr >> 11, s = rr & 2047;
          const bf16_t bv = (bf16_t)v;
          const long bh = b * 16 + hh;
          if (which == 0)      outQ[(bh * 2048 + s) * 64 + d] = bv;
          else if (which == 1) outK[(bh * 2048 + s) * 64 + d] = bv;
          else                 outV[(bh * 64 + d) * 2048 + s] = bv;
        } else {
          outF[rr * N + cc] = v + bias[cc] + res[rr * N + cc];
        }
      }
    }
  }
}

// ---------------- dual GEMM + SwiGLU epilogue ------------------------------
// BM=128, BN=64, BK=32, 4 waves (2M x 2N): per-wave 64x32 per GEMM.
__global__ __launch_bounds__(256)
void gemm_dual(const bf16_t* __restrict__ A,
               const bf16_t* __restrict__ B1t, const bf16_t* __restrict__ B2t,
               const float* __restrict__ bias1, const float* __restrict__ bias2,
               bf16_t* __restrict__ out, int M, int N, int K)
{
  __shared__ __align__(16) bf16_t As[128 * 32];
  __shared__ __align__(16) bf16_t B1s[64 * 32];
  __shared__ __align__(16) bf16_t B2s[64 * 32];
  const int tid = threadIdx.x, lane = tid & 63, w = tid >> 6;
  const int wr = w >> 1, wc = w & 1;
  const long row0 = (long)blockIdx.y * 128;
  const long col0 = (long)blockIdx.x * 64;
  const int rsub = lane >> 2;
  const int csub = (lane & 3) * 8;
  const int l15 = lane & 15;
  f32x4 acc1[4][2] = {}, acc2[4][2] = {};
  for (long k0 = 0; k0 < K; k0 += 32) {
    gll16(A   + (row0 + w * 16       + rsub) * (long)K + k0 + csub, (char*)As  + w * 1024);
    gll16(A   + (row0 + (w + 4) * 16 + rsub) * (long)K + k0 + csub, (char*)As  + (w + 4) * 1024);
    gll16(B1t + (col0 + w * 16       + rsub) * (long)K + k0 + csub, (char*)B1s + w * 1024);
    gll16(B2t + (col0 + w * 16       + rsub) * (long)K + k0 + csub, (char*)B2s + w * 1024);
    __syncthreads();
    const int kof = (lane >> 4) * 8;
    bf16x8 af[4], b1f[2], b2f[2];
    #pragma unroll
    for (int m = 0; m < 4; ++m)
      af[m] = *(const bf16x8*)(As + (wr * 64 + m * 16 + l15) * 32 + kof);
    #pragma unroll
    for (int n = 0; n < 2; ++n) {
      b1f[n] = *(const bf16x8*)(B1s + (wc * 32 + n * 16 + l15) * 32 + kof);
      b2f[n] = *(const bf16x8*)(B2s + (wc * 32 + n * 16 + l15) * 32 + kof);
    }
    #pragma unroll
    for (int m = 0; m < 4; ++m)
      #pragma unroll
      for (int n = 0; n < 2; ++n) {
        acc1[m][n] = __builtin_amdgcn_mfma_f32_16x16x32_bf16(af[m], b1f[n], acc1[m][n], 0, 0, 0);
        acc2[m][n] = __builtin_amdgcn_mfma_f32_16x16x32_bf16(af[m], b2f[n], acc2[m][n], 0, 0, 0);
      }
    __syncthreads();
  }
  #pragma unroll
  for (int m = 0; m < 4; ++m) {
    #pragma unroll
    for (int n = 0; n < 2; ++n) {
      const long cc = col0 + wc * 32 + n * 16 + l15;
      #pragma unroll
      for (int r = 0; r < 4; ++r) {
        const long rr = row0 + wr * 64 + m * 16 + (lane >> 4) * 4 + r;
        const float a = acc1[m][n][r] + bias1[cc];
        const float gt = acc2[m][n][r] + bias2[cc];
        const float sig = 1.0f / (1.0f + __expf(-a));
        out[rr * N + cc] = (bf16_t)(a * sig * gt);
      }
    }
  }
}

// ---------------- causal flash attention v3 --------------------------------
// q,k: [B,H,S,DH] bf16 ; vT: [B,H,DH,S] bf16 ; ctx: [B,S,H*DH] bf16
// grid (B*H, 16): bx = bh so linear block id % 8 == bh % 8 -> all 16 blocks of
// one (b,h) land on ONE XCD; per-XCD K/V working set = 8 bh x 512 KB = 4 MB =
// L2 capacity. Block by handles q-tiles by and 31-by (equal 34 trips/wave).
__global__ __launch_bounds__(256)
void attn_kernel(const bf16_t* __restrict__ q, const bf16_t* __restrict__ k,
                 const bf16_t* __restrict__ vT, bf16_t* __restrict__ ctx)
{
  __shared__ __align__(16) bf16_t plds[4][16][72];   // per-wave P tile [q16][t64+pad]
  const int tid = threadIdx.x, lane = tid & 63, wvi = tid >> 6;
  const int bh = blockIdx.x;
  const bf16_t* qp = q  + (long)bh * 2048 * 64;
  const bf16_t* kp = k  + (long)bh * 2048 * 64;
  const bf16_t* vp = vT + (long)bh * 64 * 2048;
  const int l15 = lane & 15, lhi = lane >> 4;
  const long b = bh >> 4;
  const int hh = bh & 15;

  #pragma unroll
  for (int seg = 0; seg < 2; ++seg) {
    const int tile = (seg == 0) ? blockIdx.y : 31 - blockIdx.y;
    const int qw0 = tile * 64 + wvi * 16;
    const int q_glob = qw0 + l15;
    bf16x8 qf[2];
    #pragma unroll
    for (int kk = 0; kk < 2; ++kk)
      qf[kk] = *(const bf16x8*)(qp + (long)(qw0 + l15) * 64 + kk * 32 + lhi * 8);
    f32x4 accO[4] = {};
    float mrow = -1e30f, lrow = 0.f;

    for (int kb = 0; kb <= qw0 + 15; kb += 64) {
      bf16x8 kf[4][2];
      #pragma unroll
      for (int n = 0; n < 4; ++n)
        #pragma unroll
        for (int kk = 0; kk < 2; ++kk)
          kf[n][kk] = *(const bf16x8*)(kp + (long)(kb + n * 16 + l15) * 64 + kk * 32 + lhi * 8);
      bf16x8 vf[4][2];
      #pragma unroll
      for (int nd = 0; nd < 4; ++nd)
        #pragma unroll
        for (int kk = 0; kk < 2; ++kk)
          vf[nd][kk] = *(const bf16x8*)(vp + (long)(nd * 16 + l15) * 2048 + kb + kk * 32 + lhi * 8);
      f32x4 accS[4] = {};
      #pragma unroll
      for (int n = 0; n < 4; ++n)
        #pragma unroll
        for (int kk = 0; kk < 2; ++kk)
          accS[n] = __builtin_amdgcn_mfma_f32_16x16x32_bf16(kf[n][kk], qf[kk], accS[n], 0, 0, 0);
      const bool needmask = (kb + 63 > qw0);
      float rmax = -1e30f;
      #pragma unroll
      for (int n = 0; n < 4; ++n)
        #pragma unroll
        for (int r = 0; r < 4; ++r) {
          float sv = accS[n][r] * 0.125f;
          if (needmask && (kb + n * 16 + lhi * 4 + r > q_glob)) sv = -1e30f;
          accS[n][r] = sv;
          rmax = fmaxf(rmax, sv);
        }
      rmax = fmaxf(rmax, __shfl_xor(rmax, 16, 64));
      rmax = fmaxf(rmax, __shfl_xor(rmax, 32, 64));
      const float mn = fmaxf(mrow, rmax);
      const float corr = exp2f((mrow - mn) * LOG2E);
      mrow = mn;
      float rsum = 0.f;
      #pragma unroll
      for (int n = 0; n < 4; ++n)
        #pragma unroll
        for (int r = 0; r < 4; ++r) {
          const float p = exp2f((accS[n][r] - mn) * LOG2E);
          accS[n][r] = p;
          rsum += p;
        }
      rsum += __shfl_xor(rsum, 16, 64);
      rsum += __shfl_xor(rsum, 32, 64);
      lrow = lrow * corr + rsum;
      #pragma unroll
      for (int nd = 0; nd < 4; ++nd)
        #pragma unroll
        for (int r = 0; r < 4; ++r) accO[nd][r] *= corr;
      #pragma unroll
      for (int n = 0; n < 4; ++n) {
        bf16x4 pk;
        #pragma unroll
        for (int r = 0; r < 4; ++r) pk[r] = (bf16_t)accS[n][r];
        *(bf16x4*)(&plds[wvi][l15][n * 16 + lhi * 4]) = pk;
      }
      #pragma unroll
      for (int kk = 0; kk < 2; ++kk) {
        const bf16x8 pf = *(const bf16x8*)(&plds[wvi][l15][kk * 32 + lhi * 8]);
        #pragma unroll
        for (int nd = 0; nd < 4; ++nd)
          accO[nd] = __builtin_amdgcn_mfma_f32_16x16x32_bf16(vf[nd][kk], pf, accO[nd], 0, 0, 0);
      }
    }
    const float inv = 1.f / lrow;
    const long crow = (b * 2048 + qw0 + l15) * 1024 + hh * 64;
    #pragma unroll
    for (int nd = 0; nd < 4; ++nd) {
      bf16x4 ok;
      #pragma unroll
      for (int r = 0; r < 4; ++r) ok[r] = (bf16_t)(accO[nd][r] * inv);
      *(bf16x4*)(ctx + crow + nd * 16 + lhi * 4) = ok;
    }
  }
}

extern "C" void kernel_launch(void* const* d_in, const int* in_sizes, int n_in,
                              void* d_out, int out_size, void* d_ws, size_t ws_size,
                              hipStream_t stream)
{
  const float* x   = (const float*)d_in[0];
  const float* wq  = (const float*)d_in[1];
  const float* wk  = (const float*)d_in[2];
  const float* wv  = (const float*)d_in[3];
  const float* wo  = (const float*)d_in[4];
  const float* bo  = (const float*)d_in[5];
  const float* w1  = (const float*)d_in[6];
  const float* b1  = (const float*)d_in[7];
  const float* w2  = (const float*)d_in[8];
  const float* b2  = (const float*)d_in[9];
  const float* w3  = (const float*)d_in[10];
  const float* b3  = (const float*)d_in[11];
  const float* g1  = (const float*)d_in[12];
  const float* be1 = (const float*)d_in[13];
  const float* g2  = (const float*)d_in[14];
  const float* be2 = (const float*)d_in[15];
  float* out = (float*)d_out;

  char* ws = (char*)d_ws;
  bf16_t* h    = (bf16_t*)(ws);                          // 16 MiB (later: ctx)
  bf16_t* qb   = (bf16_t*)(ws + 16777216L);              // 16 MiB (later: h2)
  bf16_t* kb   = (bf16_t*)(ws + 2 * 16777216L);          // 16 MiB
  bf16_t* vTb  = (bf16_t*)(ws + 3 * 16777216L);          // 16 MiB
  float*  r1   = (float*)(ws + 4 * 16777216L);           // 32 MiB
  bf16_t* ffin = (bf16_t*)(ws + 4 * 16777216L + 33554432L); // 64 MiB
  char* wbase  = ws + 4 * 16777216L + 33554432L + 67108864L;
  bf16_t* Wqkvt = (bf16_t*)(wbase);                      // [3072][1024]
  bf16_t* Wot   = (bf16_t*)(wbase + 6291456L);           // [1024][1024]
  bf16_t* W1t   = (bf16_t*)(wbase + 8388608L);           // [4096][1024]
  bf16_t* W2t   = (bf16_t*)(wbase + 16777216L);          // [4096][1024]
  bf16_t* W3t   = (bf16_t*)(wbase + 25165824L);          // [1024][4096]

  const dim3 tb(64, 4);
  transpose_cvt<<<dim3(1, 16, 16), tb, 0, stream>>>(wq, Wqkvt,            1024, 64, 65536, 65536);
  transpose_cvt<<<dim3(1, 16, 16), tb, 0, stream>>>(wk, Wqkvt + 1048576L, 1024, 64, 65536, 65536);
  transpose_cvt<<<dim3(1, 16, 16), tb, 0, stream>>>(wv, Wqkvt + 2097152L, 1024, 64, 65536, 65536);
  transpose_cvt<<<dim3(16, 16, 1), tb, 0, stream>>>(wo, Wot, 1024, 1024, 0, 0);
  transpose_cvt<<<dim3(64, 16, 1), tb, 0, stream>>>(w1, W1t, 1024, 4096, 0, 0);
  transpose_cvt<<<dim3(64, 16, 1), tb, 0, stream>>>(w2, W2t, 1024, 4096, 0, 0);
  transpose_cvt<<<dim3(16, 64, 1), tb, 0, stream>>>(w3, W3t, 4096, 1024, 0, 0);
  ln_kernel<<<8192, 256, 0, stream>>>(x, g1, be1, h);
  gemm16<0><<<dim3(24, 64), 256, 0, stream>>>(h, Wqkvt, nullptr, nullptr, nullptr,
                                              qb, kb, vTb, 8192, 3072, 1024);
  attn_kernel<<<dim3(64, 16), 256, 0, stream>>>(qb, kb, vTb, h);
  gemm16<1><<<dim3(8, 64), 256, 0, stream>>>(h, Wot, bo, x, r1,
                                             nullptr, nullptr, nullptr, 8192, 1024, 1024);
  ln_kernel<<<8192, 256, 0, stream>>>(r1, g2, be2, qb);
  gemm_dual<<<dim3(64, 64), 256, 0, stream>>>(qb, W1t, W2t, b1, b2, ffin, 8192, 4096, 1024);
  gemm16<1><<<dim3(8, 64), 256, 0, stream>>>(ffin, W3t, b3, r1, out,
                                             nullptr, nullptr, nullptr, 8192, 1024, 4096);
}

// Round 5
// 600.844 us; speedup vs baseline: 1.3341x; 1.3341x over previous
//
#include <hip/hip_runtime.h>
#include <hip/hip_bf16.h>
#include <cstdint>

// Block: B=4, S=2048, E=1024, H=16, DH=64, DF=4096.  M = B*S = 8192 rows.
// All GEMMs: C = A[M,K] * Bt[N,K]^T via mfma_f32_16x16x32_bf16, fp32 acc.

typedef __bf16 bf16_t;
typedef __attribute__((ext_vector_type(8))) __bf16 bf16x8;
typedef __attribute__((ext_vector_type(4))) __bf16 bf16x4;
typedef __attribute__((ext_vector_type(4))) float f32x4;

#define LOG2E 1.4426950408889634f

static __device__ __forceinline__ void gll16(const void* g, void* l) {
  __builtin_amdgcn_global_load_lds(
      (const __attribute__((address_space(1))) void*)g,
      (__attribute__((address_space(3))) void*)l, 16, 0, 0);
}

// ---------------- transpose + fp32->bf16 convert ----------------
__global__ __launch_bounds__(256)
void transpose_cvt(const float* __restrict__ in, bf16_t* __restrict__ out,
                   int R, int C, long in_batch, long out_batch)
{
  __shared__ float tile[64][65];
  const float* inp = in + (long)blockIdx.z * in_batch;
  bf16_t* outp = out + (long)blockIdx.z * out_batch;
  const int c0 = blockIdx.x * 64, r0 = blockIdx.y * 64;
  for (int rr = threadIdx.y; rr < 64; rr += 4)
    tile[rr][threadIdx.x] = inp[(long)(r0 + rr) * C + c0 + threadIdx.x];
  __syncthreads();
  for (int cc = threadIdx.y; cc < 64; cc += 4)
    outp[(long)(c0 + cc) * R + r0 + threadIdx.x] = (bf16_t)tile[threadIdx.x][cc];
}

// ---------------- LayerNorm (fp32 in, bf16 out) ----------------
__global__ __launch_bounds__(256)
void ln_kernel(const float* __restrict__ x, const float* __restrict__ g,
               const float* __restrict__ be, bf16_t* __restrict__ out)
{
  const long row = blockIdx.x;
  const float4 v = ((const float4*)(x + row * 1024))[threadIdx.x];
  float s  = v.x + v.y + v.z + v.w;
  float s2 = v.x*v.x + v.y*v.y + v.z*v.z + v.w*v.w;
  #pragma unroll
  for (int m = 1; m < 64; m <<= 1) {
    s  += __shfl_xor(s, m, 64);
    s2 += __shfl_xor(s2, m, 64);
  }
  __shared__ float red[8];
  const int w = threadIdx.x >> 6, lane = threadIdx.x & 63;
  if (lane == 0) { red[w] = s; red[4 + w] = s2; }
  __syncthreads();
  s  = red[0] + red[1] + red[2] + red[3];
  s2 = red[4] + red[5] + red[6] + red[7];
  const float mu = s * (1.f / 1024.f);
  const float rs = rsqrtf(s2 * (1.f / 1024.f) - mu * mu + 1e-5f);
  const int c = threadIdx.x * 4;
  bf16x4 o;
  o[0] = (bf16_t)((v.x - mu) * rs * g[c+0] + be[c+0]);
  o[1] = (bf16_t)((v.y - mu) * rs * g[c+1] + be[c+1]);
  o[2] = (bf16_t)((v.z - mu) * rs * g[c+2] + be[c+2]);
  o[3] = (bf16_t)((v.w - mu) * rs * g[c+3] + be[c+3]);
  *(bf16x4*)(out + row * 1024 + c) = o;
}

// ---------------- generic bf16 GEMM, 128x128 tile, BK=32, 4 waves ----------
template<int EPI>
__global__ __launch_bounds__(256)
void gemm16(const bf16_t* __restrict__ A, const bf16_t* __restrict__ Bt,
            const float* __restrict__ bias, const float* __restrict__ res,
            float* __restrict__ outF,
            bf16_t* __restrict__ outQ, bf16_t* __restrict__ outK, bf16_t* __restrict__ outV,
            int M, int N, int K)
{
  __shared__ __align__(16) bf16_t As[128 * 32];
  __shared__ __align__(16) bf16_t Bs[128 * 32];
  const int tid = threadIdx.x, lane = tid & 63, w = tid >> 6;
  const int wr = w >> 1, wc = w & 1;
  const long row0 = (long)blockIdx.y * 128;
  const long col0 = (long)blockIdx.x * 128;
  const int rsub = lane >> 2;
  const int csub = (lane & 3) * 8;
  f32x4 acc[4][4] = {};
  for (long k0 = 0; k0 < K; k0 += 32) {
    #pragma unroll
    for (int i = 0; i < 2; ++i) {
      const int c = i * 4 + w;
      gll16(A  + (row0 + c * 16 + rsub) * (long)K + k0 + csub, (char*)As + c * 1024);
      gll16(Bt + (col0 + c * 16 + rsub) * (long)K + k0 + csub, (char*)Bs + c * 1024);
    }
    __syncthreads();
    const int kof = (lane >> 4) * 8;
    bf16x8 af[4], bfr[4];
    #pragma unroll
    for (int m = 0; m < 4; ++m)
      af[m] = *(const bf16x8*)(As + (wr * 64 + m * 16 + (lane & 15)) * 32 + kof);
    #pragma unroll
    for (int n = 0; n < 4; ++n)
      bfr[n] = *(const bf16x8*)(Bs + (wc * 64 + n * 16 + (lane & 15)) * 32 + kof);
    #pragma unroll
    for (int m = 0; m < 4; ++m)
      #pragma unroll
      for (int n = 0; n < 4; ++n)
        acc[m][n] = __builtin_amdgcn_mfma_f32_16x16x32_bf16(af[m], bfr[n], acc[m][n], 0, 0, 0);
    __syncthreads();
  }
  #pragma unroll
  for (int m = 0; m < 4; ++m) {
    #pragma unroll
    for (int n = 0; n < 4; ++n) {
      const long cc = col0 + wc * 64 + n * 16 + (lane & 15);
      #pragma unroll
      for (int r = 0; r < 4; ++r) {
        const long rr = row0 + wr * 64 + m * 16 + (lane >> 4) * 4 + r;
        const float v = acc[m][n][r];
        if constexpr (EPI == 0) {
          const int which = (int)(cc >> 10);
          const int hh = (int)((cc >> 6) & 15);
          const int d  = (int)(cc & 63);
          const long b = rr >> 11, s = rr & 2047;
          const bf16_t bv = (bf16_t)v;
          const long bh = b * 16 + hh;
          if (which == 0)      outQ[(bh * 2048 + s) * 64 + d] = bv;
          else if (which == 1) outK[(bh * 2048 + s) * 64 + d] = bv;
          else                 outV[(bh * 64 + d) * 2048 + s] = bv;
        } else {
          outF[rr * N + cc] = v + bias[cc] + res[rr * N + cc];
        }
      }
    }
  }
}

// ---------------- dual GEMM + SwiGLU epilogue ------------------------------
// BM=128, BN=64, BK=32, 4 waves (2M x 2N): per-wave 64x32 per GEMM.
__global__ __launch_bounds__(256)
void gemm_dual(const bf16_t* __restrict__ A,
               const bf16_t* __restrict__ B1t, const bf16_t* __restrict__ B2t,
               const float* __restrict__ bias1, const float* __restrict__ bias2,
               bf16_t* __restrict__ out, int M, int N, int K)
{
  __shared__ __align__(16) bf16_t As[128 * 32];
  __shared__ __align__(16) bf16_t B1s[64 * 32];
  __shared__ __align__(16) bf16_t B2s[64 * 32];
  const int tid = threadIdx.x, lane = tid & 63, w = tid >> 6;
  const int wr = w >> 1, wc = w & 1;
  const long row0 = (long)blockIdx.y * 128;
  const long col0 = (long)blockIdx.x * 64;
  const int rsub = lane >> 2;
  const int csub = (lane & 3) * 8;
  const int l15 = lane & 15;
  f32x4 acc1[4][2] = {}, acc2[4][2] = {};
  for (long k0 = 0; k0 < K; k0 += 32) {
    gll16(A   + (row0 + w * 16       + rsub) * (long)K + k0 + csub, (char*)As  + w * 1024);
    gll16(A   + (row0 + (w + 4) * 16 + rsub) * (long)K + k0 + csub, (char*)As  + (w + 4) * 1024);
    gll16(B1t + (col0 + w * 16       + rsub) * (long)K + k0 + csub, (char*)B1s + w * 1024);
    gll16(B2t + (col0 + w * 16       + rsub) * (long)K + k0 + csub, (char*)B2s + w * 1024);
    __syncthreads();
    const int kof = (lane >> 4) * 8;
    bf16x8 af[4], b1f[2], b2f[2];
    #pragma unroll
    for (int m = 0; m < 4; ++m)
      af[m] = *(const bf16x8*)(As + (wr * 64 + m * 16 + l15) * 32 + kof);
    #pragma unroll
    for (int n = 0; n < 2; ++n) {
      b1f[n] = *(const bf16x8*)(B1s + (wc * 32 + n * 16 + l15) * 32 + kof);
      b2f[n] = *(const bf16x8*)(B2s + (wc * 32 + n * 16 + l15) * 32 + kof);
    }
    #pragma unroll
    for (int m = 0; m < 4; ++m)
      #pragma unroll
      for (int n = 0; n < 2; ++n) {
        acc1[m][n] = __builtin_amdgcn_mfma_f32_16x16x32_bf16(af[m], b1f[n], acc1[m][n], 0, 0, 0);
        acc2[m][n] = __builtin_amdgcn_mfma_f32_16x16x32_bf16(af[m], b2f[n], acc2[m][n], 0, 0, 0);
      }
    __syncthreads();
  }
  #pragma unroll
  for (int m = 0; m < 4; ++m) {
    #pragma unroll
    for (int n = 0; n < 2; ++n) {
      const long cc = col0 + wc * 32 + n * 16 + l15;
      #pragma unroll
      for (int r = 0; r < 4; ++r) {
        const long rr = row0 + wr * 64 + m * 16 + (lane >> 4) * 4 + r;
        const float a = acc1[m][n][r] + bias1[cc];
        const float gt = acc2[m][n][r] + bias2[cc];
        const float sig = 1.0f / (1.0f + __expf(-a));
        out[rr * N + cc] = (bf16_t)(a * sig * gt);
      }
    }
  }
}

// ---------------- causal flash attention v4: LDS-staged K/V ----------------
// q,k: [B,H,S,DH] bf16 ; vT: [B,H,DH,S] bf16 ; ctx: [B,S,H*DH] bf16
// grid (B*H, 16), 256 thr = 4 waves x 16 q-rows = 64-row tile; block handles
// tiles by and 31-by (33 trips, balanced). Per trip the BLOCK stages K[64][64]
// + V^T[64][64] (16 KB) into LDS via global_load_lds (double-buffered, one
// barrier/trip) -- 4x fewer global loads than per-wave fragments, scatter
// done once. 16B-chunk XOR swizzle (applied on the GLOBAL source per rule
// "both-sides-or-neither"; LDS dest linear) makes all ds_read_b128 conflict-
// free. plds chunk-swizzled likewise. LDS 40960 B -> 4 blocks/CU;
// __launch_bounds__(256,4) pins VGPR<=128 for 16 waves/CU.
__global__ __launch_bounds__(256, 4)
void attn_kernel(const bf16_t* __restrict__ q, const bf16_t* __restrict__ k,
                 const bf16_t* __restrict__ vT, bf16_t* __restrict__ ctx)
{
  __shared__ __align__(16) bf16_t Kb[2][64 * 64];
  __shared__ __align__(16) bf16_t Vb[2][64 * 64];
  __shared__ __align__(16) bf16_t plds[4][16 * 64];
  const int tid = threadIdx.x, lane = tid & 63, wvi = tid >> 6;
  const int bh = blockIdx.x;
  const bf16_t* qp = q  + (long)bh * 2048 * 64;
  const bf16_t* kp = k  + (long)bh * 2048 * 64;
  const bf16_t* vp = vT + (long)bh * 64 * 2048;
  const int l15 = lane & 15, lhi = lane >> 4;
  const long b = bh >> 4;
  const int hh = bh & 15;
  const int sw = (l15 & 7);          // read-side chunk swizzle key
  const int psw = sw << 1;           // plds 8B-chunk swizzle key

  // staging: 64 rows x 8 chunks(16B) per tile; 256 thr x 2 chunks each.
  // physical chunk cp of row r holds logical chunk cp ^ (r&7).
  const int r0s = tid >> 3, cp0 = tid & 7, cl0 = cp0 ^ (r0s & 7);
  const int r1s = (tid + 256) >> 3, cp1 = tid & 7, cl1 = cp1 ^ (r1s & 7);

  #pragma unroll
  for (int seg = 0; seg < 2; ++seg) {
    const int ts = (seg == 0) ? blockIdx.y : 31 - blockIdx.y;
    const int qw0 = ts * 64 + wvi * 16;
    const int q_glob = qw0 + l15;
    bf16x8 qf[2];
    #pragma unroll
    for (int kk = 0; kk < 2; ++kk)
      qf[kk] = *(const bf16x8*)(qp + (long)(qw0 + l15) * 64 + kk * 32 + lhi * 8);
    f32x4 accO[4] = {};
    float mrow = -1e30f, lrow = 0.f;

    // prologue stage kb=0 into buf 0
    gll16(kp + (long)(0 + r0s) * 64 + cl0 * 8, (char*)Kb[0] + tid * 16);
    gll16(vp + (long)r0s * 2048 + 0 + cl0 * 8, (char*)Vb[0] + tid * 16);
    gll16(kp + (long)(0 + r1s) * 64 + cl1 * 8, (char*)Kb[0] + (tid + 256) * 16);
    gll16(vp + (long)r1s * 2048 + 0 + cl1 * 8, (char*)Vb[0] + (tid + 256) * 16);
    __syncthreads();

    int cur = 0;
    const int kbmax = ts * 64;
    for (int kb = 0; kb <= kbmax; kb += 64) {
      if (kb + 64 <= kbmax) {        // stage next tile into the other buffer
        const int nb = kb + 64;
        gll16(kp + (long)(nb + r0s) * 64 + cl0 * 8, (char*)Kb[cur ^ 1] + tid * 16);
        gll16(vp + (long)r0s * 2048 + nb + cl0 * 8, (char*)Vb[cur ^ 1] + tid * 16);
        gll16(kp + (long)(nb + r1s) * 64 + cl1 * 8, (char*)Kb[cur ^ 1] + (tid + 256) * 16);
        gll16(vp + (long)r1s * 2048 + nb + cl1 * 8, (char*)Vb[cur ^ 1] + (tid + 256) * 16);
      }
      // ---- S^T = mfma(K, Q): accS[n][r] = S[q=l15][t = kb + n*16 + lhi*4 + r]
      f32x4 accS[4] = {};
      #pragma unroll
      for (int n = 0; n < 4; ++n) {
        const bf16_t* kr = Kb[cur] + (n * 16 + l15) * 64;
        #pragma unroll
        for (int kk = 0; kk < 2; ++kk) {
          const bf16x8 kf = *(const bf16x8*)(kr + ((kk * 4 + lhi) ^ sw) * 8);
          accS[n] = __builtin_amdgcn_mfma_f32_16x16x32_bf16(kf, qf[kk], accS[n], 0, 0, 0);
        }
      }
      const bool needmask = (kb + 63 > qw0);
      float rmax = -1e30f;
      #pragma unroll
      for (int n = 0; n < 4; ++n)
        #pragma unroll
        for (int r = 0; r < 4; ++r) {
          float sv = accS[n][r] * 0.125f;
          if (needmask && (kb + n * 16 + lhi * 4 + r > q_glob)) sv = -1e30f;
          accS[n][r] = sv;
          rmax = fmaxf(rmax, sv);
        }
      rmax = fmaxf(rmax, __shfl_xor(rmax, 16, 64));
      rmax = fmaxf(rmax, __shfl_xor(rmax, 32, 64));
      const float mn = fmaxf(mrow, rmax);
      const float corr = exp2f((mrow - mn) * LOG2E);
      mrow = mn;
      float rsum = 0.f;
      #pragma unroll
      for (int n = 0; n < 4; ++n)
        #pragma unroll
        for (int r = 0; r < 4; ++r) {
          const float p = exp2f((accS[n][r] - mn) * LOG2E);
          accS[n][r] = p;
          rsum += p;
        }
      rsum += __shfl_xor(rsum, 16, 64);
      rsum += __shfl_xor(rsum, 32, 64);
      lrow = lrow * corr + rsum;
      #pragma unroll
      for (int nd = 0; nd < 4; ++nd)
        #pragma unroll
        for (int r = 0; r < 4; ++r) accO[nd][r] *= corr;
      // ---- P row q=l15 -> plds (8B chunks, swizzled) ----
      #pragma unroll
      for (int n = 0; n < 4; ++n) {
        bf16x4 pk;
        #pragma unroll
        for (int r = 0; r < 4; ++r) pk[r] = (bf16_t)accS[n][r];
        *(bf16x4*)(&plds[wvi][l15 * 64 + ((4 * n + lhi) ^ psw) * 4]) = pk;
      }
      // ---- O^T += V^T * P^T (same-wave DS write->read) ----
      #pragma unroll
      for (int kk = 0; kk < 2; ++kk) {
        const bf16x8 pf = *(const bf16x8*)(&plds[wvi][l15 * 64 + ((8 * kk + 2 * lhi) ^ psw) * 4]);
        #pragma unroll
        for (int nd = 0; nd < 4; ++nd) {
          const bf16x8 vf = *(const bf16x8*)(Vb[cur] + (nd * 16 + l15) * 64 + ((kk * 4 + lhi) ^ sw) * 8);
          accO[nd] = __builtin_amdgcn_mfma_f32_16x16x32_bf16(vf, pf, accO[nd], 0, 0, 0);
        }
      }
      __syncthreads();               // drains gll16 queue + joins waves
      cur ^= 1;
    }
    // epilogue: accO[nd][r] = O^T[d = nd*16 + lhi*4 + r][q = l15]
    const float inv = 1.f / lrow;
    const long crow = (b * 2048 + qw0 + l15) * 1024 + hh * 64;
    #pragma unroll
    for (int nd = 0; nd < 4; ++nd) {
      bf16x4 ok;
      #pragma unroll
      for (int r = 0; r < 4; ++r) ok[r] = (bf16_t)(accO[nd][r] * inv);
      *(bf16x4*)(ctx + crow + nd * 16 + lhi * 4) = ok;
    }
  }
}

extern "C" void kernel_launch(void* const* d_in, const int* in_sizes, int n_in,
                              void* d_out, int out_size, void* d_ws, size_t ws_size,
                              hipStream_t stream)
{
  const float* x   = (const float*)d_in[0];
  const float* wq  = (const float*)d_in[1];
  const float* wk  = (const float*)d_in[2];
  const float* wv  = (const float*)d_in[3];
  const float* wo  = (const float*)d_in[4];
  const float* bo  = (const float*)d_in[5];
  const float* w1  = (const float*)d_in[6];
  const float* b1  = (const float*)d_in[7];
  const float* w2  = (const float*)d_in[8];
  const float* b2  = (const float*)d_in[9];
  const float* w3  = (const float*)d_in[10];
  const float* b3  = (const float*)d_in[11];
  const float* g1  = (const float*)d_in[12];
  const float* be1 = (const float*)d_in[13];
  const float* g2  = (const float*)d_in[14];
  const float* be2 = (const float*)d_in[15];
  float* out = (float*)d_out;

  char* ws = (char*)d_ws;
  bf16_t* h    = (bf16_t*)(ws);                          // 16 MiB (later: ctx)
  bf16_t* qb   = (bf16_t*)(ws + 16777216L);              // 16 MiB (later: h2)
  bf16_t* kb   = (bf16_t*)(ws + 2 * 16777216L);          // 16 MiB
  bf16_t* vTb  = (bf16_t*)(ws + 3 * 16777216L);          // 16 MiB
  float*  r1   = (float*)(ws + 4 * 16777216L);           // 32 MiB
  bf16_t* ffin = (bf16_t*)(ws + 4 * 16777216L + 33554432L); // 64 MiB
  char* wbase  = ws + 4 * 16777216L + 33554432L + 67108864L;
  bf16_t* Wqkvt = (bf16_t*)(wbase);                      // [3072][1024]
  bf16_t* Wot   = (bf16_t*)(wbase + 6291456L);           // [1024][1024]
  bf16_t* W1t   = (bf16_t*)(wbase + 8388608L);           // [4096][1024]
  bf16_t* W2t   = (bf16_t*)(wbase + 16777216L);          // [4096][1024]
  bf16_t* W3t   = (bf16_t*)(wbase + 25165824L);          // [1024][4096]

  const dim3 tb(64, 4);
  transpose_cvt<<<dim3(1, 16, 16), tb, 0, stream>>>(wq, Wqkvt,            1024, 64, 65536, 65536);
  transpose_cvt<<<dim3(1, 16, 16), tb, 0, stream>>>(wk, Wqkvt + 1048576L, 1024, 64, 65536, 65536);
  transpose_cvt<<<dim3(1, 16, 16), tb, 0, stream>>>(wv, Wqkvt + 2097152L, 1024, 64, 65536, 65536);
  transpose_cvt<<<dim3(16, 16, 1), tb, 0, stream>>>(wo, Wot, 1024, 1024, 0, 0);
  transpose_cvt<<<dim3(64, 16, 1), tb, 0, stream>>>(w1, W1t, 1024, 4096, 0, 0);
  transpose_cvt<<<dim3(64, 16, 1), tb, 0, stream>>>(w2, W2t, 1024, 4096, 0, 0);
  transpose_cvt<<<dim3(16, 64, 1), tb, 0, stream>>>(w3, W3t, 4096, 1024, 0, 0);
  ln_kernel<<<8192, 256, 0, stream>>>(x, g1, be1, h);
  gemm16<0><<<dim3(24, 64), 256, 0, stream>>>(h, Wqkvt, nullptr, nullptr, nullptr,
                                              qb, kb, vTb, 8192, 3072, 1024);
  attn_kernel<<<dim3(64, 16), 256, 0, stream>>>(qb, kb, vTb, h);
  gemm16<1><<<dim3(8, 64), 256, 0, stream>>>(h, Wot, bo, x, r1,
                                             nullptr, nullptr, nullptr, 8192, 1024, 1024);
  ln_kernel<<<8192, 256, 0, stream>>>(r1, g2, be2, qb);
  gemm_dual<<<dim3(64, 64), 256, 0, stream>>>(qb, W1t, W2t, b1, b2, ffin, 8192, 4096, 1024);
  gemm16<1><<<dim3(8, 64), 256, 0, stream>>>(ffin, W3t, b3, r1, out,
                                             nullptr, nullptr, nullptr, 8192, 1024, 4096);
}

// Round 6
// 536.332 us; speedup vs baseline: 1.4945x; 1.1203x over previous
//
#include <hip/hip_runtime.h>
#include <hip/hip_bf16.h>
#include <cstdint>

// Block: B=4, S=2048, E=1024, H=16, DH=64, DF=4096.  M = B*S = 8192 rows.
// All GEMMs: C = A[M,K] * Bt[N,K]^T via mfma_f32_16x16x32_bf16, fp32 acc.

typedef __bf16 bf16_t;
typedef __attribute__((ext_vector_type(8))) __bf16 bf16x8;
typedef __attribute__((ext_vector_type(4))) __bf16 bf16x4;
typedef __attribute__((ext_vector_type(4))) float f32x4;

#define LOG2E 1.4426950408889634f

static __device__ __forceinline__ void gll16(const void* g, void* l) {
  __builtin_amdgcn_global_load_lds(
      (const __attribute__((address_space(1))) void*)g,
      (__attribute__((address_space(3))) void*)l, 16, 0, 0);
}

// ---------------- transpose + fp32->bf16 convert ----------------
__global__ __launch_bounds__(256)
void transpose_cvt(const float* __restrict__ in, bf16_t* __restrict__ out,
                   int R, int C, long in_batch, long out_batch)
{
  __shared__ float tile[64][65];
  const float* inp = in + (long)blockIdx.z * in_batch;
  bf16_t* outp = out + (long)blockIdx.z * out_batch;
  const int c0 = blockIdx.x * 64, r0 = blockIdx.y * 64;
  for (int rr = threadIdx.y; rr < 64; rr += 4)
    tile[rr][threadIdx.x] = inp[(long)(r0 + rr) * C + c0 + threadIdx.x];
  __syncthreads();
  for (int cc = threadIdx.y; cc < 64; cc += 4)
    outp[(long)(c0 + cc) * R + r0 + threadIdx.x] = (bf16_t)tile[threadIdx.x][cc];
}

// ---------------- LayerNorm (fp32 in, bf16 out) ----------------
__global__ __launch_bounds__(256)
void ln_kernel(const float* __restrict__ x, const float* __restrict__ g,
               const float* __restrict__ be, bf16_t* __restrict__ out)
{
  const long row = blockIdx.x;
  const float4 v = ((const float4*)(x + row * 1024))[threadIdx.x];
  float s  = v.x + v.y + v.z + v.w;
  float s2 = v.x*v.x + v.y*v.y + v.z*v.z + v.w*v.w;
  #pragma unroll
  for (int m = 1; m < 64; m <<= 1) {
    s  += __shfl_xor(s, m, 64);
    s2 += __shfl_xor(s2, m, 64);
  }
  __shared__ float red[8];
  const int w = threadIdx.x >> 6, lane = threadIdx.x & 63;
  if (lane == 0) { red[w] = s; red[4 + w] = s2; }
  __syncthreads();
  s  = red[0] + red[1] + red[2] + red[3];
  s2 = red[4] + red[5] + red[6] + red[7];
  const float mu = s * (1.f / 1024.f);
  const float rs = rsqrtf(s2 * (1.f / 1024.f) - mu * mu + 1e-5f);
  const int c = threadIdx.x * 4;
  bf16x4 o;
  o[0] = (bf16_t)((v.x - mu) * rs * g[c+0] + be[c+0]);
  o[1] = (bf16_t)((v.y - mu) * rs * g[c+1] + be[c+1]);
  o[2] = (bf16_t)((v.z - mu) * rs * g[c+2] + be[c+2]);
  o[3] = (bf16_t)((v.w - mu) * rs * g[c+3] + be[c+3]);
  *(bf16x4*)(out + row * 1024 + c) = o;
}

// ---------------- generic bf16 GEMM, 128x128 tile, BK=32, 4 waves ----------
// v2: double-buffered LDS staging; next tile's global_load_lds is issued
// BEFORE the current tile's compute, ONE barrier per K-step (joins readers of
// buf[cur] AND drains the DMA into buf[cur^1]).  DMA latency hides under
// 16 MFMA + 8 ds_read.  LDS 32 KB -> 5 blocks/CU.
template<int EPI>
__global__ __launch_bounds__(256)
void gemm16(const bf16_t* __restrict__ A, const bf16_t* __restrict__ Bt,
            const float* __restrict__ bias, const float* __restrict__ res,
            float* __restrict__ outF,
            bf16_t* __restrict__ outQ, bf16_t* __restrict__ outK, bf16_t* __restrict__ outV,
            int M, int N, int K)
{
  __shared__ __align__(16) bf16_t As[2][128 * 32];
  __shared__ __align__(16) bf16_t Bs[2][128 * 32];
  const int tid = threadIdx.x, lane = tid & 63, w = tid >> 6;
  const int wr = w >> 1, wc = w & 1;
  const long row0 = (long)blockIdx.y * 128;
  const long col0 = (long)blockIdx.x * 128;
  const int rsub = lane >> 2;
  const int csub = (lane & 3) * 8;
  f32x4 acc[4][4] = {};

  auto stage = [&](long k0, int buf) {
    #pragma unroll
    for (int i = 0; i < 2; ++i) {
      const int c = i * 4 + w;
      gll16(A  + (row0 + c * 16 + rsub) * (long)K + k0 + csub, (char*)As[buf] + c * 1024);
      gll16(Bt + (col0 + c * 16 + rsub) * (long)K + k0 + csub, (char*)Bs[buf] + c * 1024);
    }
  };

  stage(0, 0);
  __syncthreads();
  int cur = 0;
  for (long k0 = 0; k0 < K; k0 += 32) {
    if (k0 + 32 < K) stage(k0 + 32, cur ^ 1);
    const int kof = (lane >> 4) * 8;
    bf16x8 af[4], bfr[4];
    #pragma unroll
    for (int m = 0; m < 4; ++m)
      af[m] = *(const bf16x8*)(As[cur] + (wr * 64 + m * 16 + (lane & 15)) * 32 + kof);
    #pragma unroll
    for (int n = 0; n < 4; ++n)
      bfr[n] = *(const bf16x8*)(Bs[cur] + (wc * 64 + n * 16 + (lane & 15)) * 32 + kof);
    #pragma unroll
    for (int m = 0; m < 4; ++m)
      #pragma unroll
      for (int n = 0; n < 4; ++n)
        acc[m][n] = __builtin_amdgcn_mfma_f32_16x16x32_bf16(af[m], bfr[n], acc[m][n], 0, 0, 0);
    __syncthreads();
    cur ^= 1;
  }
  #pragma unroll
  for (int m = 0; m < 4; ++m) {
    #pragma unroll
    for (int n = 0; n < 4; ++n) {
      const long cc = col0 + wc * 64 + n * 16 + (lane & 15);
      #pragma unroll
      for (int r = 0; r < 4; ++r) {
        const long rr = row0 + wr * 64 + m * 16 + (lane >> 4) * 4 + r;
        const float v = acc[m][n][r];
        if constexpr (EPI == 0) {
          const int which = (int)(cc >> 10);
          const int hh = (int)((cc >> 6) & 15);
          const int d  = (int)(cc & 63);
          const long b = rr >> 11, s = rr & 2047;
          const bf16_t bv = (bf16_t)v;
          const long bh = b * 16 + hh;
          if (which == 0)      outQ[(bh * 2048 + s) * 64 + d] = bv;
          else if (which == 1) outK[(bh * 2048 + s) * 64 + d] = bv;
          else                 outV[(bh * 64 + d) * 2048 + s] = bv;
        } else {
          outF[rr * N + cc] = v + bias[cc] + res[rr * N + cc];
        }
      }
    }
  }
}

// ---------------- dual GEMM + SwiGLU epilogue ------------------------------
// BM=128, BN=64, BK=32, 4 waves (2M x 2N); same dbuf/stage-early/1-barrier
// structure as gemm16 v2.  LDS 32 KB.
__global__ __launch_bounds__(256)
void gemm_dual(const bf16_t* __restrict__ A,
               const bf16_t* __restrict__ B1t, const bf16_t* __restrict__ B2t,
               const float* __restrict__ bias1, const float* __restrict__ bias2,
               bf16_t* __restrict__ out, int M, int N, int K)
{
  __shared__ __align__(16) bf16_t As[2][128 * 32];
  __shared__ __align__(16) bf16_t B1s[2][64 * 32];
  __shared__ __align__(16) bf16_t B2s[2][64 * 32];
  const int tid = threadIdx.x, lane = tid & 63, w = tid >> 6;
  const int wr = w >> 1, wc = w & 1;
  const long row0 = (long)blockIdx.y * 128;
  const long col0 = (long)blockIdx.x * 64;
  const int rsub = lane >> 2;
  const int csub = (lane & 3) * 8;
  const int l15 = lane & 15;
  f32x4 acc1[4][2] = {}, acc2[4][2] = {};

  auto stage = [&](long k0, int buf) {
    gll16(A   + (row0 + w * 16       + rsub) * (long)K + k0 + csub, (char*)As[buf]  + w * 1024);
    gll16(A   + (row0 + (w + 4) * 16 + rsub) * (long)K + k0 + csub, (char*)As[buf]  + (w + 4) * 1024);
    gll16(B1t + (col0 + w * 16       + rsub) * (long)K + k0 + csub, (char*)B1s[buf] + w * 1024);
    gll16(B2t + (col0 + w * 16       + rsub) * (long)K + k0 + csub, (char*)B2s[buf] + w * 1024);
  };

  stage(0, 0);
  __syncthreads();
  int cur = 0;
  for (long k0 = 0; k0 < K; k0 += 32) {
    if (k0 + 32 < K) stage(k0 + 32, cur ^ 1);
    const int kof = (lane >> 4) * 8;
    bf16x8 af[4], b1f[2], b2f[2];
    #pragma unroll
    for (int m = 0; m < 4; ++m)
      af[m] = *(const bf16x8*)(As[cur] + (wr * 64 + m * 16 + l15) * 32 + kof);
    #pragma unroll
    for (int n = 0; n < 2; ++n) {
      b1f[n] = *(const bf16x8*)(B1s[cur] + (wc * 32 + n * 16 + l15) * 32 + kof);
      b2f[n] = *(const bf16x8*)(B2s[cur] + (wc * 32 + n * 16 + l15) * 32 + kof);
    }
    #pragma unroll
    for (int m = 0; m < 4; ++m)
      #pragma unroll
      for (int n = 0; n < 2; ++n) {
        acc1[m][n] = __builtin_amdgcn_mfma_f32_16x16x32_bf16(af[m], b1f[n], acc1[m][n], 0, 0, 0);
        acc2[m][n] = __builtin_amdgcn_mfma_f32_16x16x32_bf16(af[m], b2f[n], acc2[m][n], 0, 0, 0);
      }
    __syncthreads();
    cur ^= 1;
  }
  #pragma unroll
  for (int m = 0; m < 4; ++m) {
    #pragma unroll
    for (int n = 0; n < 2; ++n) {
      const long cc = col0 + wc * 32 + n * 16 + l15;
      #pragma unroll
      for (int r = 0; r < 4; ++r) {
        const long rr = row0 + wr * 64 + m * 16 + (lane >> 4) * 4 + r;
        const float a = acc1[m][n][r] + bias1[cc];
        const float gt = acc2[m][n][r] + bias2[cc];
        const float sig = 1.0f / (1.0f + __expf(-a));
        out[rr * N + cc] = (bf16_t)(a * sig * gt);
      }
    }
  }
}

// ---------------- causal flash attention v4: LDS-staged K/V ----------------
// (unchanged from round 5 -- it left the top-5)
__global__ __launch_bounds__(256, 4)
void attn_kernel(const bf16_t* __restrict__ q, const bf16_t* __restrict__ k,
                 const bf16_t* __restrict__ vT, bf16_t* __restrict__ ctx)
{
  __shared__ __align__(16) bf16_t Kb[2][64 * 64];
  __shared__ __align__(16) bf16_t Vb[2][64 * 64];
  __shared__ __align__(16) bf16_t plds[4][16 * 64];
  const int tid = threadIdx.x, lane = tid & 63, wvi = tid >> 6;
  const int bh = blockIdx.x;
  const bf16_t* qp = q  + (long)bh * 2048 * 64;
  const bf16_t* kp = k  + (long)bh * 2048 * 64;
  const bf16_t* vp = vT + (long)bh * 64 * 2048;
  const int l15 = lane & 15, lhi = lane >> 4;
  const long b = bh >> 4;
  const int hh = bh & 15;
  const int sw = (l15 & 7);
  const int psw = sw << 1;

  const int r0s = tid >> 3, cp0 = tid & 7, cl0 = cp0 ^ (r0s & 7);
  const int r1s = (tid + 256) >> 3, cp1 = tid & 7, cl1 = cp1 ^ (r1s & 7);

  #pragma unroll
  for (int seg = 0; seg < 2; ++seg) {
    const int ts = (seg == 0) ? blockIdx.y : 31 - blockIdx.y;
    const int qw0 = ts * 64 + wvi * 16;
    const int q_glob = qw0 + l15;
    bf16x8 qf[2];
    #pragma unroll
    for (int kk = 0; kk < 2; ++kk)
      qf[kk] = *(const bf16x8*)(qp + (long)(qw0 + l15) * 64 + kk * 32 + lhi * 8);
    f32x4 accO[4] = {};
    float mrow = -1e30f, lrow = 0.f;

    gll16(kp + (long)(0 + r0s) * 64 + cl0 * 8, (char*)Kb[0] + tid * 16);
    gll16(vp + (long)r0s * 2048 + 0 + cl0 * 8, (char*)Vb[0] + tid * 16);
    gll16(kp + (long)(0 + r1s) * 64 + cl1 * 8, (char*)Kb[0] + (tid + 256) * 16);
    gll16(vp + (long)r1s * 2048 + 0 + cl1 * 8, (char*)Vb[0] + (tid + 256) * 16);
    __syncthreads();

    int cur = 0;
    const int kbmax = ts * 64;
    for (int kb = 0; kb <= kbmax; kb += 64) {
      if (kb + 64 <= kbmax) {
        const int nb = kb + 64;
        gll16(kp + (long)(nb + r0s) * 64 + cl0 * 8, (char*)Kb[cur ^ 1] + tid * 16);
        gll16(vp + (long)r0s * 2048 + nb + cl0 * 8, (char*)Vb[cur ^ 1] + tid * 16);
        gll16(kp + (long)(nb + r1s) * 64 + cl1 * 8, (char*)Kb[cur ^ 1] + (tid + 256) * 16);
        gll16(vp + (long)r1s * 2048 + nb + cl1 * 8, (char*)Vb[cur ^ 1] + (tid + 256) * 16);
      }
      f32x4 accS[4] = {};
      #pragma unroll
      for (int n = 0; n < 4; ++n) {
        const bf16_t* kr = Kb[cur] + (n * 16 + l15) * 64;
        #pragma unroll
        for (int kk = 0; kk < 2; ++kk) {
          const bf16x8 kf = *(const bf16x8*)(kr + ((kk * 4 + lhi) ^ sw) * 8);
          accS[n] = __builtin_amdgcn_mfma_f32_16x16x32_bf16(kf, qf[kk], accS[n], 0, 0, 0);
        }
      }
      const bool needmask = (kb + 63 > qw0);
      float rmax = -1e30f;
      #pragma unroll
      for (int n = 0; n < 4; ++n)
        #pragma unroll
        for (int r = 0; r < 4; ++r) {
          float sv = accS[n][r] * 0.125f;
          if (needmask && (kb + n * 16 + lhi * 4 + r > q_glob)) sv = -1e30f;
          accS[n][r] = sv;
          rmax = fmaxf(rmax, sv);
        }
      rmax = fmaxf(rmax, __shfl_xor(rmax, 16, 64));
      rmax = fmaxf(rmax, __shfl_xor(rmax, 32, 64));
      const float mn = fmaxf(mrow, rmax);
      const float corr = exp2f((mrow - mn) * LOG2E);
      mrow = mn;
      float rsum = 0.f;
      #pragma unroll
      for (int n = 0; n < 4; ++n)
        #pragma unroll
        for (int r = 0; r < 4; ++r) {
          const float p = exp2f((accS[n][r] - mn) * LOG2E);
          accS[n][r] = p;
          rsum += p;
        }
      rsum += __shfl_xor(rsum, 16, 64);
      rsum += __shfl_xor(rsum, 32, 64);
      lrow = lrow * corr + rsum;
      #pragma unroll
      for (int nd = 0; nd < 4; ++nd)
        #pragma unroll
        for (int r = 0; r < 4; ++r) accO[nd][r] *= corr;
      #pragma unroll
      for (int n = 0; n < 4; ++n) {
        bf16x4 pk;
        #pragma unroll
        for (int r = 0; r < 4; ++r) pk[r] = (bf16_t)accS[n][r];
        *(bf16x4*)(&plds[wvi][l15 * 64 + ((4 * n + lhi) ^ psw) * 4]) = pk;
      }
      #pragma unroll
      for (int kk = 0; kk < 2; ++kk) {
        const bf16x8 pf = *(const bf16x8*)(&plds[wvi][l15 * 64 + ((8 * kk + 2 * lhi) ^ psw) * 4]);
        #pragma unroll
        for (int nd = 0; nd < 4; ++nd) {
          const bf16x8 vf = *(const bf16x8*)(Vb[cur] + (nd * 16 + l15) * 64 + ((kk * 4 + lhi) ^ sw) * 8);
          accO[nd] = __builtin_amdgcn_mfma_f32_16x16x32_bf16(vf, pf, accO[nd], 0, 0, 0);
        }
      }
      __syncthreads();
      cur ^= 1;
    }
    const float inv = 1.f / lrow;
    const long crow = (b * 2048 + qw0 + l15) * 1024 + hh * 64;
    #pragma unroll
    for (int nd = 0; nd < 4; ++nd) {
      bf16x4 ok;
      #pragma unroll
      for (int r = 0; r < 4; ++r) ok[r] = (bf16_t)(accO[nd][r] * inv);
      *(bf16x4*)(ctx + crow + nd * 16 + lhi * 4) = ok;
    }
  }
}

extern "C" void kernel_launch(void* const* d_in, const int* in_sizes, int n_in,
                              void* d_out, int out_size, void* d_ws, size_t ws_size,
                              hipStream_t stream)
{
  const float* x   = (const float*)d_in[0];
  const float* wq  = (const float*)d_in[1];
  const float* wk  = (const float*)d_in[2];
  const float* wv  = (const float*)d_in[3];
  const float* wo  = (const float*)d_in[4];
  const float* bo  = (const float*)d_in[5];
  const float* w1  = (const float*)d_in[6];
  const float* b1  = (const float*)d_in[7];
  const float* w2  = (const float*)d_in[8];
  const float* b2  = (const float*)d_in[9];
  const float* w3  = (const float*)d_in[10];
  const float* b3  = (const float*)d_in[11];
  const float* g1  = (const float*)d_in[12];
  const float* be1 = (const float*)d_in[13];
  const float* g2  = (const float*)d_in[14];
  const float* be2 = (const float*)d_in[15];
  float* out = (float*)d_out;

  char* ws = (char*)d_ws;
  bf16_t* h    = (bf16_t*)(ws);                          // 16 MiB (later: ctx)
  bf16_t* qb   = (bf16_t*)(ws + 16777216L);              // 16 MiB (later: h2)
  bf16_t* kb   = (bf16_t*)(ws + 2 * 16777216L);          // 16 MiB
  bf16_t* vTb  = (bf16_t*)(ws + 3 * 16777216L);          // 16 MiB
  float*  r1   = (float*)(ws + 4 * 16777216L);           // 32 MiB
  bf16_t* ffin = (bf16_t*)(ws + 4 * 16777216L + 33554432L); // 64 MiB
  char* wbase  = ws + 4 * 16777216L + 33554432L + 67108864L;
  bf16_t* Wqkvt = (bf16_t*)(wbase);                      // [3072][1024]
  bf16_t* Wot   = (bf16_t*)(wbase + 6291456L);           // [1024][1024]
  bf16_t* W1t   = (bf16_t*)(wbase + 8388608L);           // [4096][1024]
  bf16_t* W2t   = (bf16_t*)(wbase + 16777216L);          // [4096][1024]
  bf16_t* W3t   = (bf16_t*)(wbase + 25165824L);          // [1024][4096]

  const dim3 tb(64, 4);
  transpose_cvt<<<dim3(1, 16, 16), tb, 0, stream>>>(wq, Wqkvt,            1024, 64, 65536, 65536);
  transpose_cvt<<<dim3(1, 16, 16), tb, 0, stream>>>(wk, Wqkvt + 1048576L, 1024, 64, 65536, 65536);
  transpose_cvt<<<dim3(1, 16, 16), tb, 0, stream>>>(wv, Wqkvt + 2097152L, 1024, 64, 65536, 65536);
  transpose_cvt<<<dim3(16, 16, 1), tb, 0, stream>>>(wo, Wot, 1024, 1024, 0, 0);
  transpose_cvt<<<dim3(64, 16, 1), tb, 0, stream>>>(w1, W1t, 1024, 4096, 0, 0);
  transpose_cvt<<<dim3(64, 16, 1), tb, 0, stream>>>(w2, W2t, 1024, 4096, 0, 0);
  transpose_cvt<<<dim3(16, 64, 1), tb, 0, stream>>>(w3, W3t, 4096, 1024, 0, 0);
  ln_kernel<<<8192, 256, 0, stream>>>(x, g1, be1, h);
  gemm16<0><<<dim3(24, 64), 256, 0, stream>>>(h, Wqkvt, nullptr, nullptr, nullptr,
                                              qb, kb, vTb, 8192, 3072, 1024);
  attn_kernel<<<dim3(64, 16), 256, 0, stream>>>(qb, kb, vTb, h);
  gemm16<1><<<dim3(8, 64), 256, 0, stream>>>(h, Wot, bo, x, r1,
                                             nullptr, nullptr, nullptr, 8192, 1024, 1024);
  ln_kernel<<<8192, 256, 0, stream>>>(r1, g2, be2, qb);
  gemm_dual<<<dim3(64, 64), 256, 0, stream>>>(qb, W1t, W2t, b1, b2, ffin, 8192, 4096, 1024);
  gemm16<1><<<dim3(8, 64), 256, 0, stream>>>(ffin, W3t, b3, r1, out,
                                             nullptr, nullptr, nullptr, 8192, 1024, 4096);
}